// Round 1
// baseline (212.395 us; speedup 1.0000x reference)
//
#include <hip/hip_runtime.h>

typedef __attribute__((ext_vector_type(8))) short short8;
typedef __attribute__((ext_vector_type(4))) float float4v;
typedef __attribute__((ext_vector_type(4))) unsigned int uint4v;

__device__ __forceinline__ unsigned short f2bf(float f) {
  unsigned int u = __float_as_uint(f);
  u += 0x7fffu + ((u >> 16) & 1u);   // round-to-nearest-even
  return (unsigned short)(u >> 16);
}
__device__ __forceinline__ float bf2f(unsigned short h) {
  return __uint_as_float(((unsigned int)h) << 16);
}

// x: (2,96,32,64,64) f32.  Sites: (b,dz,hy,wx), block = one W-row (32 sites).
// k' permutation: k' = c*8 + i, i = di*4+hi*2+wi  (k_orig = i*96 + c)
__global__ __launch_bounds__(256, 2)
void pm_kernel(const float* __restrict__ x, const float* __restrict__ gamma,
               const float* __restrict__ beta, const float* __restrict__ w_red,
               float* __restrict__ out) {
  __shared__ __align__(16) unsigned short Y[32][776];   // 49664 B, bf16 bits
  __shared__ __align__(16) unsigned short Bs[192][40];  // 15360 B, B^T frag layout
  __shared__ float gammaP[768];
  __shared__ float betaP[768];

  const int tid = threadIdx.x;
  const int bid = blockIdx.x;
  const int b  = bid >> 9;
  const int dz = (bid >> 5) & 15;
  const int hy = bid & 31;

  const float* xb = x + (size_t)b * 12582912u + (size_t)dz * 8192u + (size_t)hy * 128u;

  // gamma/beta into LDS in k' order
  for (int t = tid; t < 768; t += 256) {
    int ko = (t & 7) * 96 + (t >> 3);
    gammaP[t] = gamma[ko];
    betaP[t]  = beta[ko];
  }

  // Phase 1: gather x -> Y[site][k'] bf16 (float4 coalesced, u32-pair LDS stores)
#pragma unroll
  for (int it = 0; it < 24; ++it) {
    int idx4 = it * 256 + tid;        // 0..6143
    int r  = idx4 >> 4;               // row: c*4 + di*2 + hi   (0..383)
    int c  = r >> 2;
    int di = (r >> 1) & 1;
    int hi = r & 1;
    int w0 = (idx4 & 15) << 2;        // 0..60
    float4 v = *(const float4*)(xb + (size_t)c * 131072u + di * 4096 + hi * 64 + w0);
    int wx0 = (idx4 & 15) << 1;       // even site
    int k0  = c * 8 + di * 4 + hi * 2; // even k'
    unsigned int p01 = (unsigned int)f2bf(v.x) | ((unsigned int)f2bf(v.y) << 16);
    unsigned int p23 = (unsigned int)f2bf(v.z) | ((unsigned int)f2bf(v.w) << 16);
    *(unsigned int*)&Y[wx0][k0]     = p01;   // (wx0, k0), (wx0, k0+1)
    *(unsigned int*)&Y[wx0 + 1][k0] = p23;
  }
  __syncthreads();

  // Phase 2: LN stats — 8 lanes per site, each covers 96 elems; keep vals in regs
  const int m   = tid >> 3;
  const int sub = tid & 7;
  float sum = 0.f, sq = 0.f;
  short8 vals[12];
#pragma unroll
  for (int j = 0; j < 12; ++j) {
    short8 v = *(const short8*)&Y[m][sub * 96 + j * 8];
    vals[j] = v;
#pragma unroll
    for (int e = 0; e < 8; ++e) {
      float f = bf2f((unsigned short)v[e]);
      sum += f; sq += f * f;
    }
  }
#pragma unroll
  for (int off = 1; off < 8; off <<= 1) {
    sum += __shfl_xor(sum, off, 64);
    sq  += __shfl_xor(sq,  off, 64);
  }
  const float mu  = sum * (1.f / 768.f);
  const float var = sq * (1.f / 768.f) - mu * mu;
  const float rs  = rsqrtf(var + 1e-5f);

  // Phase 3: normalize in place (same-thread ranges -> no barrier needed before)
#pragma unroll
  for (int j = 0; j < 12; ++j) {
    int kp = sub * 96 + j * 8;
    short8 v = vals[j];
    short8 o;
#pragma unroll
    for (int e = 0; e < 8; ++e) {
      float f  = bf2f((unsigned short)v[e]);
      float nv = (f - mu) * rs * gammaP[kp + e] + betaP[kp + e];
      o[e] = (short)f2bf(nv);
    }
    *(short8*)&Y[m][kp] = o;
  }
  __syncthreads();

  // GEMM: 32x192 = (32x768) @ (768x192), K-steps of 32, B staged fp32->bf16
  const int lane = tid & 63;
  const int wave = tid >> 6;
  const int lrow = lane & 15;
  const int lq   = lane >> 4;

  float4v acc[2][3];
#pragma unroll
  for (int i2 = 0; i2 < 2; ++i2)
#pragma unroll
    for (int j2 = 0; j2 < 3; ++j2)
#pragma unroll
      for (int r = 0; r < 4; ++r) acc[i2][j2][r] = 0.f;

  for (int kc = 0; kc < 24; ++kc) {
    if (kc) __syncthreads();   // protect prev frag reads from restage
    // stage Bs[n][k_local]: task id -> (qb, n); 8 k' = 8 octants i, fixed c
#pragma unroll
    for (int it = 0; it < 3; ++it) {
      int id = it * 256 + tid;        // 0..767
      int qb = id / 192;              // 0..3
      int n  = id - qb * 192;
      const float* wp = w_red + (size_t)(kc * 4 + qb) * 192 + n;  // c = kc*4+qb
      uint4v pk;
#pragma unroll
      for (int jj = 0; jj < 4; ++jj) {
        float a0 = wp[(size_t)(2 * jj)     * 18432];  // k_orig = i*96+c, row stride 96*192
        float a1 = wp[(size_t)(2 * jj + 1) * 18432];
        pk[jj] = (unsigned int)f2bf(a0) | ((unsigned int)f2bf(a1) << 16);
      }
      *(uint4v*)&Bs[n][qb * 8] = pk;
    }
    __syncthreads();

    short8 a0 = *(const short8*)&Y[lrow][kc * 32 + lq * 8];
    short8 a1 = *(const short8*)&Y[16 + lrow][kc * 32 + lq * 8];
#pragma unroll
    for (int t3 = 0; t3 < 3; ++t3) {
      int nt = wave * 3 + t3;
      short8 bf = *(const short8*)&Bs[nt * 16 + lrow][lq * 8];
      acc[0][t3] = __builtin_amdgcn_mfma_f32_16x16x32_bf16(a0, bf, acc[0][t3], 0, 0, 0);
      acc[1][t3] = __builtin_amdgcn_mfma_f32_16x16x32_bf16(a1, bf, acc[1][t3], 0, 0, 0);
    }
  }

  // Epilogue: frags -> LDS (Cs[o][site], stride 40) -> coalesced float4 stores
  __syncthreads();
  float* Cs = (float*)&Y[0][0];  // 192*40*4 = 30720 B <= 49664 B
#pragma unroll
  for (int mt = 0; mt < 2; ++mt)
#pragma unroll
    for (int t3 = 0; t3 < 3; ++t3) {
      int ng = (wave * 3 + t3) * 16 + lrow;      // output channel o
#pragma unroll
      for (int r = 0; r < 4; ++r) {
        Cs[ng * 40 + mt * 16 + lq * 4 + r] = acc[mt][t3][r];  // site = mt*16+lq*4+r
      }
    }
  __syncthreads();

  float* ob = out + (size_t)b * 3145728u + (size_t)dz * 1024u + (size_t)hy * 32u;
#pragma unroll
  for (int it = 0; it < 6; ++it) {
    int idx4 = it * 256 + tid;   // 0..1535
    int o  = idx4 >> 3;
    int wq = idx4 & 7;
    float4 vv = *(const float4*)&Cs[o * 40 + wq * 4];
    *(float4*)(ob + (size_t)o * 16384u + wq * 4) = vv;
  }
}

extern "C" void kernel_launch(void* const* d_in, const int* in_sizes, int n_in,
                              void* d_out, int out_size, void* d_ws, size_t ws_size,
                              hipStream_t stream) {
  const float* x     = (const float*)d_in[0];
  const float* gamma = (const float*)d_in[1];
  const float* beta  = (const float*)d_in[2];
  const float* w_red = (const float*)d_in[3];
  float* out = (float*)d_out;
  pm_kernel<<<dim3(1024), dim3(256), 0, stream>>>(x, gamma, beta, w_red, out);
}

// Round 2
// 204.627 us; speedup vs baseline: 1.0380x; 1.0380x over previous
//
#include <hip/hip_runtime.h>

typedef __attribute__((ext_vector_type(8))) short short8;
typedef __attribute__((ext_vector_type(4))) float float4v;

__device__ __forceinline__ unsigned short f2bf(float f) {
  unsigned int u = __float_as_uint(f);
  u += 0x7fffu + ((u >> 16) & 1u);   // round-to-nearest-even
  return (unsigned short)(u >> 16);
}
__device__ __forceinline__ float bf2f(unsigned short h) {
  return __uint_as_float(((unsigned int)h) << 16);
}

// ---------------- prep: w' = gamma*w -> bf16 [n][k'] + colsum + bias ----------
// k' = c*8 + i (i = di*4+hi*2+wi), k_orig = i*96 + c
__global__ __launch_bounds__(256)
void prep_kernel(const float* __restrict__ w_red, const float* __restrict__ gamma,
                 const float* __restrict__ beta, unsigned short* __restrict__ w_bf,
                 float* __restrict__ colsum, float* __restrict__ bias) {
  const int n = blockIdx.x;       // 0..191
  const int t = threadIdx.x;      // 0..255
  float cs = 0.f, bs = 0.f;
#pragma unroll
  for (int j = 0; j < 3; ++j) {
    int kp = j * 256 + t;                       // k' 0..767
    int ko = (kp & 7) * 96 + (kp >> 3);         // original k
    float w = w_red[(size_t)ko * 192 + n];
    unsigned short v = f2bf(gamma[ko] * w);
    w_bf[(size_t)n * 768 + kp] = v;
    cs += bf2f(v);
    bs += beta[ko] * w;
  }
#pragma unroll
  for (int off = 1; off < 64; off <<= 1) {
    cs += __shfl_xor(cs, off, 64);
    bs += __shfl_xor(bs, off, 64);
  }
  __shared__ float red[2][4];
  const int wave = t >> 6;
  if ((t & 63) == 0) { red[0][wave] = cs; red[1][wave] = bs; }
  __syncthreads();
  if (t == 0) {
    colsum[n] = red[0][0] + red[0][1] + red[0][2] + red[0][3];
    bias[n]   = red[1][0] + red[1][1] + red[1][2] + red[1][3];
  }
}

// ---------------- main: gather+stats -> barrier-free MFMA K-loop -> epilogue --
__global__ __launch_bounds__(256, 3)
void pm_kernel(const float* __restrict__ x, const unsigned short* __restrict__ w_bf,
               const float* __restrict__ colsum, const float* __restrict__ bias,
               float* __restrict__ out) {
  __shared__ __align__(16) unsigned short Y[32][776];   // 49664 B
  __shared__ float4 part4[4][16];                       // 1024 B: per-wave stat partials
  __shared__ float smu[32], srs[32];

  const int tid = threadIdx.x;
  const int bid = blockIdx.x;
  const int b  = bid >> 9;
  const int dz = (bid >> 5) & 15;
  const int hy = bid & 31;

  const float* xb = x + (size_t)b * 12582912u + (size_t)dz * 8192u + (size_t)hy * 128u;

  // Phase 1: gather x -> Y[site][k'] bf16, fused per-site stat partials.
  // idx4&15 == tid&15 -> each thread always touches sites 2*(tid&15), +1.
  float sum0 = 0.f, sq0 = 0.f, sum1 = 0.f, sq1 = 0.f;
#pragma unroll
  for (int it = 0; it < 24; ++it) {
    int idx4 = it * 256 + tid;        // 0..6143
    int r  = idx4 >> 4;               // c*4 + di*2 + hi
    int c  = r >> 2;
    int di = (r >> 1) & 1;
    int hi = r & 1;
    int w0 = (idx4 & 15) << 2;
    float4 v = *(const float4*)(xb + (size_t)c * 131072u + di * 4096 + hi * 64 + w0);
    int wx0 = (idx4 & 15) << 1;
    int k0  = c * 8 + di * 4 + hi * 2;
    unsigned int p01 = (unsigned int)f2bf(v.x) | ((unsigned int)f2bf(v.y) << 16);
    unsigned int p23 = (unsigned int)f2bf(v.z) | ((unsigned int)f2bf(v.w) << 16);
    *(unsigned int*)&Y[wx0][k0]     = p01;
    *(unsigned int*)&Y[wx0 + 1][k0] = p23;
    sum0 += v.x + v.y;  sq0 += v.x * v.x + v.y * v.y;
    sum1 += v.z + v.w;  sq1 += v.z * v.z + v.w * v.w;
  }
  // reduce across the 4 lanes (l, l+16, l+32, l+48) sharing a site pair
#pragma unroll
  for (int off = 16; off < 64; off <<= 1) {
    sum0 += __shfl_xor(sum0, off, 64);  sq0 += __shfl_xor(sq0, off, 64);
    sum1 += __shfl_xor(sum1, off, 64);  sq1 += __shfl_xor(sq1, off, 64);
  }
  const int lane = tid & 63;
  const int wave = tid >> 6;
  if (lane < 16) part4[wave][lane] = make_float4(sum0, sq0, sum1, sq1);
  __syncthreads();   // Y ready + partials ready

  if (tid < 32) {
    int sp = tid >> 1, odd = tid & 1;
    float s = 0.f, q = 0.f;
#pragma unroll
    for (int w = 0; w < 4; ++w) {
      float4 p = part4[w][sp];
      s += odd ? p.z : p.x;
      q += odd ? p.w : p.y;
    }
    float mu  = s * (1.f / 768.f);
    float var = q * (1.f / 768.f) - mu * mu;
    smu[tid] = mu;
    srs[tid] = rsqrtf(var + 1e-5f);
  }

  // GEMM: 32x192 = (32x768)@(768x192), raw bf16 A, B-fragments straight from
  // global w_bf (L2-resident). Zero barriers; B prefetched one kc ahead.
  const int lrow = lane & 15;
  const int lq   = lane >> 4;

  float4v acc[2][3];
#pragma unroll
  for (int i2 = 0; i2 < 2; ++i2)
#pragma unroll
    for (int j2 = 0; j2 < 3; ++j2)
#pragma unroll
      for (int r = 0; r < 4; ++r) acc[i2][j2][r] = 0.f;

  const unsigned short* wrow[3];
#pragma unroll
  for (int t3 = 0; t3 < 3; ++t3)
    wrow[t3] = w_bf + (size_t)((wave * 3 + t3) * 16 + lrow) * 768 + lq * 8;

  short8 bcur[3];
#pragma unroll
  for (int t3 = 0; t3 < 3; ++t3) bcur[t3] = *(const short8*)(wrow[t3]);

  for (int kc = 0; kc < 24; ++kc) {
    int kn = (kc < 23) ? kc + 1 : kc;
    short8 bnext[3];
#pragma unroll
    for (int t3 = 0; t3 < 3; ++t3) bnext[t3] = *(const short8*)(wrow[t3] + kn * 32);
    short8 a0 = *(const short8*)&Y[lrow][kc * 32 + lq * 8];
    short8 a1 = *(const short8*)&Y[16 + lrow][kc * 32 + lq * 8];
#pragma unroll
    for (int t3 = 0; t3 < 3; ++t3) {
      acc[0][t3] = __builtin_amdgcn_mfma_f32_16x16x32_bf16(a0, bcur[t3], acc[0][t3], 0, 0, 0);
      acc[1][t3] = __builtin_amdgcn_mfma_f32_16x16x32_bf16(a1, bcur[t3], acc[1][t3], 0, 0, 0);
    }
#pragma unroll
    for (int t3 = 0; t3 < 3; ++t3) bcur[t3] = bnext[t3];
  }

  // Epilogue: LN correction out = rs*(acc - mu*colsum) + bias, then
  // LDS transpose -> coalesced float4 stores.
  __syncthreads();   // all A-fragment reads done; Y reusable as Cs
  float* Cs = (float*)&Y[0][0];   // 192*40*4 = 30720 B
#pragma unroll
  for (int t3 = 0; t3 < 3; ++t3) {
    int ng = (wave * 3 + t3) * 16 + lrow;   // output channel
    float cs_n = colsum[ng];
    float bi_n = bias[ng];
#pragma unroll
    for (int mt = 0; mt < 2; ++mt)
#pragma unroll
      for (int r = 0; r < 4; ++r) {
        int m = mt * 16 + lq * 4 + r;       // site
        float v = srs[m] * (acc[mt][t3][r] - smu[m] * cs_n) + bi_n;
        Cs[ng * 40 + m] = v;
      }
  }
  __syncthreads();

  float* ob = out + (size_t)b * 3145728u + (size_t)dz * 1024u + (size_t)hy * 32u;
#pragma unroll
  for (int it = 0; it < 6; ++it) {
    int idx4 = it * 256 + tid;   // 0..1535
    int o  = idx4 >> 3;
    int wq = idx4 & 7;
    float4 vv = *(const float4*)&Cs[o * 40 + wq * 4];
    *(float4*)(ob + (size_t)o * 16384u + wq * 4) = vv;
  }
}

extern "C" void kernel_launch(void* const* d_in, const int* in_sizes, int n_in,
                              void* d_out, int out_size, void* d_ws, size_t ws_size,
                              hipStream_t stream) {
  const float* x     = (const float*)d_in[0];
  const float* gamma = (const float*)d_in[1];
  const float* beta  = (const float*)d_in[2];
  const float* w_red = (const float*)d_in[3];
  float* out = (float*)d_out;

  unsigned short* w_bf = (unsigned short*)d_ws;            // 192*768*2 = 294912 B
  float* colsum = (float*)((char*)d_ws + 294912);          // 192 f32
  float* bias   = colsum + 192;                            // 192 f32

  prep_kernel<<<dim3(192), dim3(256), 0, stream>>>(w_red, gamma, beta, w_bf, colsum, bias);
  pm_kernel<<<dim3(1024), dim3(256), 0, stream>>>(x, w_bf, colsum, bias, out);
}

// Round 3
// 190.081 us; speedup vs baseline: 1.1174x; 1.0765x over previous
//
#include <hip/hip_runtime.h>

typedef __attribute__((ext_vector_type(8))) short short8;
typedef __attribute__((ext_vector_type(4))) float float4v;

__device__ __forceinline__ unsigned short f2bf(float f) {
  unsigned int u = __float_as_uint(f);
  u += 0x7fffu + ((u >> 16) & 1u);   // round-to-nearest-even
  return (unsigned short)(u >> 16);
}
__device__ __forceinline__ float bf2f(unsigned short h) {
  return __uint_as_float(((unsigned int)h) << 16);
}

// ---------------- prep: w' = gamma*w -> bf16 [n][k'] + colsum + bias ----------
// k' = c*8 + i (i = di*4+hi*2+wi), k_orig = i*96 + c
__global__ __launch_bounds__(256)
void prep_kernel(const float* __restrict__ w_red, const float* __restrict__ gamma,
                 const float* __restrict__ beta, unsigned short* __restrict__ w_bf,
                 float* __restrict__ colsum, float* __restrict__ bias) {
  const int n = blockIdx.x;       // 0..191
  const int t = threadIdx.x;      // 0..255
  float cs = 0.f, bs = 0.f;
#pragma unroll
  for (int j = 0; j < 3; ++j) {
    int kp = j * 256 + t;                       // k' 0..767
    int ko = (kp & 7) * 96 + (kp >> 3);         // original k
    float w = w_red[(size_t)ko * 192 + n];
    unsigned short v = f2bf(gamma[ko] * w);
    w_bf[(size_t)n * 768 + kp] = v;
    cs += bf2f(v);
    bs += beta[ko] * w;
  }
#pragma unroll
  for (int off = 1; off < 64; off <<= 1) {
    cs += __shfl_xor(cs, off, 64);
    bs += __shfl_xor(bs, off, 64);
  }
  __shared__ float red[2][4];
  const int wave = t >> 6;
  if ((t & 63) == 0) { red[0][wave] = cs; red[1][wave] = bs; }
  __syncthreads();
  if (t == 0) {
    colsum[n] = red[0][0] + red[0][1] + red[0][2] + red[0][3];
    bias[n]   = red[1][0] + red[1][1] + red[1][2] + red[1][3];
  }
}

// ---------------- main: MLP-maximized gather -> MFMA K-loop -> epilogue ------
__global__ __launch_bounds__(256, 3)
void pm_kernel(const float* __restrict__ x, const unsigned short* __restrict__ w_bf,
               const float* __restrict__ colsum, const float* __restrict__ bias,
               float* __restrict__ out) {
  __shared__ __align__(16) unsigned short Y[32][776];   // 49664 B
  __shared__ float4 part4[4][16];
  __shared__ float smu[32], srs[32];

  const int tid = threadIdx.x;
  const int bid = blockIdx.x;
  const int b  = bid >> 9;
  const int dz = (bid >> 5) & 15;
  const int hy = bid & 31;

  const float* xb = x + (size_t)b * 12582912u + (size_t)dz * 8192u + (size_t)hy * 128u;

  // Per-thread constant decomposition: idx4 = it*256+tid ->
  //   r0=tid>>4 gives (c0,di,hi); w0=(tid&15)*4; c = it*4+c0 -> addr stride 2MB.
  const int r0 = tid >> 4;
  const int c0 = r0 >> 2;
  const int di = (r0 >> 1) & 1;
  const int hi = r0 & 1;
  const int w0 = (tid & 15) << 2;
  const float* xp = xb + (size_t)c0 * 131072u + di * 4096 + hi * 64 + w0;

  // Phase 1a: issue ALL 24 global loads before any consumption (max MLP).
  float4 v[24];
#pragma unroll
  for (int it = 0; it < 24; ++it)
    v[it] = *(const float4*)(xp + (size_t)it * 524288u);

  // B-fragment pointers + first two K-steps issued inside the same window.
  const int lane = tid & 63;
  const int wave = tid >> 6;
  const int lrow = lane & 15;
  const int lq   = lane >> 4;
  const unsigned short* wrow[3];
#pragma unroll
  for (int t3 = 0; t3 < 3; ++t3)
    wrow[t3] = w_bf + (size_t)((wave * 3 + t3) * 16 + lrow) * 768 + lq * 8;
  short8 b0[3], b1[3];
#pragma unroll
  for (int t3 = 0; t3 < 3; ++t3) b0[t3] = *(const short8*)(wrow[t3]);
#pragma unroll
  for (int t3 = 0; t3 < 3; ++t3) b1[t3] = *(const short8*)(wrow[t3] + 32);

  // Phase 1b: convert + LDS store + fused stats.
  const int wx0 = (tid & 15) << 1;
  const int k00 = c0 * 8 + di * 4 + hi * 2;
  float sum0 = 0.f, sq0 = 0.f, sum1 = 0.f, sq1 = 0.f;
#pragma unroll
  for (int it = 0; it < 24; ++it) {
    float4 vv = v[it];
    unsigned int p01 = (unsigned int)f2bf(vv.x) | ((unsigned int)f2bf(vv.y) << 16);
    unsigned int p23 = (unsigned int)f2bf(vv.z) | ((unsigned int)f2bf(vv.w) << 16);
    int k0 = it * 32 + k00;
    *(unsigned int*)&Y[wx0][k0]     = p01;
    *(unsigned int*)&Y[wx0 + 1][k0] = p23;
    sum0 += vv.x + vv.y;  sq0 += vv.x * vv.x + vv.y * vv.y;
    sum1 += vv.z + vv.w;  sq1 += vv.z * vv.z + vv.w * vv.w;
  }
#pragma unroll
  for (int off = 16; off < 64; off <<= 1) {
    sum0 += __shfl_xor(sum0, off, 64);  sq0 += __shfl_xor(sq0, off, 64);
    sum1 += __shfl_xor(sum1, off, 64);  sq1 += __shfl_xor(sq1, off, 64);
  }
  if (lane < 16) part4[wave][lane] = make_float4(sum0, sq0, sum1, sq1);
  __syncthreads();   // Y + partials ready

  if (tid < 32) {
    int sp = tid >> 1, odd = tid & 1;
    float s = 0.f, q = 0.f;
#pragma unroll
    for (int w = 0; w < 4; ++w) {
      float4 p = part4[w][sp];
      s += odd ? p.z : p.x;
      q += odd ? p.w : p.y;
    }
    float mu  = s * (1.f / 768.f);
    float var = q * (1.f / 768.f) - mu * mu;
    smu[tid] = mu;
    srs[tid] = rsqrtf(var + 1e-5f);
  }

  // GEMM K-loop: raw bf16 A from LDS, B from global (L2-resident), depth-2
  // prefetch, zero barriers.
  float4v acc[2][3];
#pragma unroll
  for (int i2 = 0; i2 < 2; ++i2)
#pragma unroll
    for (int j2 = 0; j2 < 3; ++j2)
#pragma unroll
      for (int r = 0; r < 4; ++r) acc[i2][j2][r] = 0.f;

  for (int kc = 0; kc < 24; ++kc) {
    int kn = (kc + 2 <= 23) ? kc + 2 : 23;
    short8 b2[3];
#pragma unroll
    for (int t3 = 0; t3 < 3; ++t3) b2[t3] = *(const short8*)(wrow[t3] + kn * 32);
    short8 a0 = *(const short8*)&Y[lrow][kc * 32 + lq * 8];
    short8 a1 = *(const short8*)&Y[16 + lrow][kc * 32 + lq * 8];
#pragma unroll
    for (int t3 = 0; t3 < 3; ++t3) {
      acc[0][t3] = __builtin_amdgcn_mfma_f32_16x16x32_bf16(a0, b0[t3], acc[0][t3], 0, 0, 0);
      acc[1][t3] = __builtin_amdgcn_mfma_f32_16x16x32_bf16(a1, b0[t3], acc[1][t3], 0, 0, 0);
    }
#pragma unroll
    for (int t3 = 0; t3 < 3; ++t3) { b0[t3] = b1[t3]; b1[t3] = b2[t3]; }
  }

  // Hoist per-channel constants before the barrier.
  float cs_n[3], bi_n[3];
#pragma unroll
  for (int t3 = 0; t3 < 3; ++t3) {
    int ng = (wave * 3 + t3) * 16 + lrow;
    cs_n[t3] = colsum[ng];
    bi_n[t3] = bias[ng];
  }

  __syncthreads();   // all A-fragment reads done; Y reusable as Cs
  float* Cs = (float*)&Y[0][0];   // 192*40*4 = 30720 B
#pragma unroll
  for (int t3 = 0; t3 < 3; ++t3) {
    int ng = (wave * 3 + t3) * 16 + lrow;
#pragma unroll
    for (int mt = 0; mt < 2; ++mt)
#pragma unroll
      for (int r = 0; r < 4; ++r) {
        int m = mt * 16 + lq * 4 + r;
        float vv = srs[m] * (acc[mt][t3][r] - smu[m] * cs_n[t3]) + bi_n[t3];
        Cs[ng * 40 + m] = vv;
      }
  }
  __syncthreads();

  float* ob = out + (size_t)b * 3145728u + (size_t)dz * 1024u + (size_t)hy * 32u;
#pragma unroll
  for (int it = 0; it < 6; ++it) {
    int idx4 = it * 256 + tid;   // 0..1535
    int o  = idx4 >> 3;
    int wq = idx4 & 7;
    float4 vv = *(const float4*)&Cs[o * 40 + wq * 4];
    *(float4*)(ob + (size_t)o * 16384u + wq * 4) = vv;
  }
}

extern "C" void kernel_launch(void* const* d_in, const int* in_sizes, int n_in,
                              void* d_out, int out_size, void* d_ws, size_t ws_size,
                              hipStream_t stream) {
  const float* x     = (const float*)d_in[0];
  const float* gamma = (const float*)d_in[1];
  const float* beta  = (const float*)d_in[2];
  const float* w_red = (const float*)d_in[3];
  float* out = (float*)d_out;

  unsigned short* w_bf = (unsigned short*)d_ws;            // 192*768*2 = 294912 B
  float* colsum = (float*)((char*)d_ws + 294912);          // 192 f32
  float* bias   = colsum + 192;                            // 192 f32

  prep_kernel<<<dim3(192), dim3(256), 0, stream>>>(w_red, gamma, beta, w_bf, colsum, bias);
  pm_kernel<<<dim3(1024), dim3(256), 0, stream>>>(x, w_bf, colsum, bias, out);
}